// Round 2
// baseline (132.135 us; speedup 1.0000x reference)
//
#include <hip/hip_runtime.h>

// SelfAttention2D: B=4, N=4096, C=256, R=32, fp32 in/out.
// out = gamma * ((softmax_axis1(f g^T) h) w_v) + x.
// 3 kernels: k_fgh (projections, self-packs weight frags), k_colsum
// (softmax-axis=1 final bias -log2(colsum)), k_pvout (S^T + normalized exp2
// via MFMA C-operand bias + in-register PV + w_v projection + residual).
// f pre-scaled by log2(e) -> raw v_exp. |s|*log2e < 64 so no max pass;
// P = exp2(s' - lg2cs) <= 1 (better numerics than old h-rescale scheme).
// R6 lesson: grid.sync() ~50us at 512 blocks — block-local fusion only.
// R7 lesson: PV chain (QK->exp->LDS->PV) is latency-bound; keep ILP-4/wave.
// R8 lesson: scattered b16 LDS packs are conflict-expensive; dest-coalesce.
// R11: pvout TLP 4 waves/SIMD via 512-thread blocks (8 m-eighth waves).
// R12: PV via mfma_f32_16x16x16bf16_1k — its A-frag layout (lane: row=col,
// k=q*4+j) EQUALS the S^T 16x16 C/D layout, so exp2(d)->bfpack feeds PV
// directly in-register; P^T LDS round-trip deleted. NEUTRAL vs R11 => pvout
// inner chain was not the critical path.
// R13: 5 kernels -> 3. Arithmetic floor of all kernels ~30us vs 123us
// measured, all kernels individually <43us (top-5 dispatches are harness
// fills) => suspect per-stage boundary overhead + redundant passes.
// k_prep folded into consumers (fgh/pvout pack weights from L2 themselves);
// k_scaleh eliminated: colsum writes -log2(colsum) final bias, pvout feeds
// it as MFMA C-operand so exp2 output is pre-normalized (R10's failure was
// the per-block merge cost; direct final-bias load has none).

#define BB 4
#define NN 4096
#define CC 256
#define RR 32
#define LOG2E 1.44269504088896340736f

typedef short short8 __attribute__((ext_vector_type(8)));            // 8 bf16
typedef short short4v __attribute__((ext_vector_type(4)));           // 4 bf16
typedef unsigned short ushort8 __attribute__((ext_vector_type(8)));
typedef float floatx4 __attribute__((ext_vector_type(4)));           // MFMA C/D

#define MFMA16 __builtin_amdgcn_mfma_f32_16x16x32_bf16
#define MFMA16K __builtin_amdgcn_mfma_f32_16x16x16bf16_1k

static __device__ __forceinline__ unsigned short f2bf(float f) {
  union { float f; unsigned u; } v; v.f = f;
  const unsigned r = v.u + 0x7fffu + ((v.u >> 16) & 1u);  // RNE
  return (unsigned short)(r >> 16);
}
// pack trunc-bf16(lo), trunc-bf16(hi) into one uint via v_perm_b32
static __device__ __forceinline__ unsigned bfpack(float lo, float hi) {
  return __builtin_amdgcn_perm(__float_as_uint(hi), __float_as_uint(lo), 0x07060302u);
}

// --------------- k_fgh: f,g,h = x @ {wf,wg,wh}; weights packed in-block
__global__ __launch_bounds__(256) void k_fgh(
    const float* __restrict__ x, const float* __restrict__ wf,
    const float* __restrict__ wg, const float* __restrict__ wh,
    unsigned short* __restrict__ f16, unsigned short* __restrict__ g16,
    unsigned short* __restrict__ hT16) {
  __shared__ unsigned short wflds[24576];  // 48 KB packed B-frags
  const int tid = threadIdx.x, lane = tid & 63, wave = tid >> 6;
  const int col = lane & 15, q = lane >> 4;
  {  // in-block weight pack: dest-coalesced LDS writes, L2-resident src reads
    const float* mats[3] = {wf, wg, wh};
#pragma unroll
    for (int mat = 0; mat < 3; ++mat) {
      const float* w = mats[mat];
#pragma unroll 4
      for (int i = 0; i < 32; ++i) {
        const int idx = mat * 8192 + i * 256 + tid;
        const int fid = (idx >> 9) & 15;
        const int kc = fid >> 1, nt = fid & 1;
        const int l2 = (idx >> 3) & 63;
        const int c2 = l2 & 15, q2 = l2 >> 4;
        const int j = idx & 7;
        wflds[idx] = f2bf(w[(kc * 32 + q2 * 8 + j) * RR + nt * 16 + c2]);
      }
    }
  }
  const int t0 = blockIdx.x * 64 + wave * 16;
  short8 af[8];
  const float* xr = x + (long)(t0 + col) * CC + q * 8;
#pragma unroll
  for (int kc = 0; kc < 8; ++kc) {
    float tmp[8];
    *(float4*)(tmp) = *(const float4*)(xr + kc * 32);
    *(float4*)(tmp + 4) = *(const float4*)(xr + kc * 32 + 4);
    short8 o;
#pragma unroll
    for (int j = 0; j < 8; ++j) o[j] = (short)f2bf(tmp[j]);
    af[kc] = o;
  }
  __syncthreads();
  const floatx4 zero = {0.f, 0.f, 0.f, 0.f};
  floatx4 acc[3][2];
#pragma unroll
  for (int m = 0; m < 3; ++m) { acc[m][0] = zero; acc[m][1] = zero; }
#pragma unroll
  for (int kc = 0; kc < 8; ++kc) {
#pragma unroll
    for (int mat = 0; mat < 3; ++mat) {
#pragma unroll
      for (int nt = 0; nt < 2; ++nt) {
        const short8 bf = *(const short8*)(wflds + (mat * 16 + kc * 2 + nt) * 512 + lane * 8);
        acc[mat][nt] = MFMA16(af[kc], bf, acc[mat][nt], 0, 0, 0);
      }
    }
  }
  const int b = t0 >> 12;
#pragma unroll
  for (int nt = 0; nt < 2; ++nt) {
#pragma unroll
    for (int r = 0; r < 4; ++r) {
      const int tok = t0 + q * 4 + r;
      const int n = nt * 16 + col;
      f16[(long)tok * RR + n] = f2bf(acc[0][nt][r] * LOG2E);
      g16[(long)tok * RR + n] = f2bf(acc[1][nt][r]);
      // hT stored interleaved within each 32-m chunk: logical m = hi*16+qq*4+j
      // lands at s = qq*8 + hi*4 + j (so pvout's short8 @ m0+q*8 yields both
      // K=16 B-frags). Here qq=q, j=r, hi=(tok>>4)&1.
      const int tl = tok & (NN - 1);
      const int sp = (tl & ~31) | (q << 3) | ((tl & 16) >> 2) | r;
      hT16[((long)b * RR + n) * NN + sp] = f2bf(acc[2][nt][r]);
    }
  }
}

// ------- k_colsum: nlg2cs[b][m] = -log2( sum_n exp2(s'[n,m]) )  (final)
// block = 32 m-columns; 4 waves split the n range; LDS cross-wave reduce.
__global__ __launch_bounds__(256) void k_colsum(
    const unsigned short* __restrict__ f16, const unsigned short* __restrict__ g16,
    float* __restrict__ nlg2cs) {
  __shared__ float red[4][32];
  const int tid = threadIdx.x, lane = tid & 63, wave = tid >> 6;
  const int col = lane & 15, q = lane >> 4;
  const int b = blockIdx.x >> 7;
  const int m0 = (blockIdx.x & 127) * 32;
  const short8 bg1 = *(const short8*)(g16 + ((long)(b * NN + m0 + col)) * RR + q * 8);
  const short8 bg2 = *(const short8*)(g16 + ((long)(b * NN + m0 + 16 + col)) * RR + q * 8);
  const floatx4 zero = {0.f, 0.f, 0.f, 0.f};
  float s1 = 0.f, s2 = 0.f;
  const unsigned short* fb = f16 + ((long)b * NN + wave * (NN / 4)) * RR;
#pragma unroll 4
  for (int n = 0; n < NN / 4; n += 16) {
    const short8 af = *(const short8*)(fb + (long)(n + col) * RR + q * 8);
    const floatx4 d1 = MFMA16(af, bg1, zero, 0, 0, 0);
    const floatx4 d2 = MFMA16(af, bg2, zero, 0, 0, 0);
    s1 += __builtin_amdgcn_exp2f(d1[0]) + __builtin_amdgcn_exp2f(d1[1]) +
          __builtin_amdgcn_exp2f(d1[2]) + __builtin_amdgcn_exp2f(d1[3]);
    s2 += __builtin_amdgcn_exp2f(d2[0]) + __builtin_amdgcn_exp2f(d2[1]) +
          __builtin_amdgcn_exp2f(d2[2]) + __builtin_amdgcn_exp2f(d2[3]);
  }
  s1 += __shfl_xor(s1, 16); s1 += __shfl_xor(s1, 32);
  s2 += __shfl_xor(s2, 16); s2 += __shfl_xor(s2, 32);
  if (lane < 16) {
    red[wave][lane] = s1;
    red[wave][lane + 16] = s2;
  }
  __syncthreads();
  if (tid < 32) {
    const float cs = red[0][tid] + red[1][tid] + red[2][tid] + red[3][tid];
    nlg2cs[(long)b * NN + m0 + tid] = -__builtin_amdgcn_logf(cs);
  }
}

// --------- k_pvout: 512-thread block = 32 tokens; 8 waves = m-eighths.
// S^T MFMA with C = -lg2cs[m] broadcast -> exp2(d) = P in (0,1], already
// normalized; S^T C/D layout IS the 16x16x16 A-frag layout, so PV runs
// fully in-register. wv frags packed into LDS in the prologue.
__global__ __launch_bounds__(512, 4) void k_pvout(
    const unsigned short* __restrict__ f16, const unsigned short* __restrict__ g16,
    const unsigned short* __restrict__ hT16, const float* __restrict__ nlg2cs,
    const float* __restrict__ wv, const float* __restrict__ x,
    const float* __restrict__ gamma, float* __restrict__ out) {
  __shared__ float ylds[8][32 * 36];    // 36 KB: per-wave y partials
  __shared__ float sc_all[8][16 * 36];  // 18 KB: epilogue store-swizzle scratch
  __shared__ unsigned short wvlds[8192];  // 16 KB: wv B-frags
  const int tid = threadIdx.x, lane = tid & 63, wave = tid >> 6;  // 0..7
  const int col = lane & 15, q = lane >> 4;
  const int b = blockIdx.x >> 7;
  const int t0 = (blockIdx.x & 127) * 32;  // token base (in-batch), 32 tokens
  const floatx4 zero = {0.f, 0.f, 0.f, 0.f};
  {  // pack wv into B-frag LDS layout (read after the pre-epilogue barrier)
#pragma unroll 4
    for (int i = 0; i < 16; ++i) {
      const int idx = i * 512 + tid;
      const int t = idx >> 9;
      const int l2 = (idx >> 3) & 63;
      const int c2 = l2 & 15, q2 = l2 >> 4;
      const int j = idx & 7;
      wvlds[idx] = f2bf(wv[(q2 * 8 + j) * CC + t * 16 + c2]);
    }
  }
  // B-frags of S^T: f rows for the block's 32 tokens (loop-invariant)
  const short8 af1 = *(const short8*)(f16 + ((long)(b * NN + t0 + col)) * RR + q * 8);
  const short8 af2 = *(const short8*)(f16 + ((long)(b * NN + t0 + 16 + col)) * RR + q * 8);
  floatx4 a11 = zero, a12 = zero, a21 = zero, a22 = zero;
  const unsigned short* gb = g16 + (long)b * NN * RR;
  const unsigned short* hb = hT16 + (long)b * RR * NN;
  const float* csb = nlg2cs + (long)b * NN;
  const int mq = wave * 512;  // this wave's m-eighth
#pragma unroll 2
  for (int mi = 0; mi < 512; mi += 32) {
    const int m0 = mq + mi;
    const short8 bg1 = *(const short8*)(gb + (long)(m0 + col) * RR + q * 8);
    const short8 bg2 = *(const short8*)(gb + (long)(m0 + 16 + col) * RR + q * 8);
    // interleaved hT: elements 0..3 = h'[m0+q*4+j][r], 4..7 = h'[m0+16+q*4+j][r]
    const short8 hv1 = *(const short8*)(hb + (long)col * NN + m0 + q * 8);
    const short8 hv2 = *(const short8*)(hb + (long)(col + 16) * NN + m0 + q * 8);
    // softmax bias as MFMA C-operand: lane reg r <-> m = m0 + q*4 + r
    const floatx4 cm0 = *(const floatx4*)(csb + m0 + q * 4);
    const floatx4 cm1 = *(const floatx4*)(csb + m0 + 16 + q * 4);
    // S^T + bias: A=g(m rows), B=f(n cols) -> lane: s'[n=col][m=m0+q*4+r]-lg2cs
    const floatx4 d00 = MFMA16(bg1, af1, cm0, 0, 0, 0);  // n-blk 0,  m-blk 0
    const floatx4 d01 = MFMA16(bg2, af1, cm1, 0, 0, 0);  // n-blk 0,  m-blk 16
    const floatx4 d10 = MFMA16(bg1, af2, cm0, 0, 0, 0);  // n-blk 16, m-blk 0
    const floatx4 d11 = MFMA16(bg2, af2, cm1, 0, 0, 0);  // n-blk 16, m-blk 16
    // P = exp2(d) in (0,1], packed in-register as 16x16x16 A-frags (k=q*4+j)
    union PU { unsigned u[2]; short4v s; } p00, p01, p10, p11;
    p00.u[0] = bfpack(__builtin_amdgcn_exp2f(d00[0]), __builtin_amdgcn_exp2f(d00[1]));
    p00.u[1] = bfpack(__builtin_amdgcn_exp2f(d00[2]), __builtin_amdgcn_exp2f(d00[3]));
    p01.u[0] = bfpack(__builtin_amdgcn_exp2f(d01[0]), __builtin_amdgcn_exp2f(d01[1]));
    p01.u[1] = bfpack(__builtin_amdgcn_exp2f(d01[2]), __builtin_amdgcn_exp2f(d01[3]));
    p10.u[0] = bfpack(__builtin_amdgcn_exp2f(d10[0]), __builtin_amdgcn_exp2f(d10[1]));
    p10.u[1] = bfpack(__builtin_amdgcn_exp2f(d10[2]), __builtin_amdgcn_exp2f(d10[3]));
    p11.u[0] = bfpack(__builtin_amdgcn_exp2f(d11[0]), __builtin_amdgcn_exp2f(d11[1]));
    p11.u[1] = bfpack(__builtin_amdgcn_exp2f(d11[2]), __builtin_amdgcn_exp2f(d11[3]));
    const short4v bh1lo = __builtin_shufflevector(hv1, hv1, 0, 1, 2, 3);
    const short4v bh1hi = __builtin_shufflevector(hv1, hv1, 4, 5, 6, 7);
    const short4v bh2lo = __builtin_shufflevector(hv2, hv2, 0, 1, 2, 3);
    const short4v bh2hi = __builtin_shufflevector(hv2, hv2, 4, 5, 6, 7);
    // PV: y[n][r] += P[n][m] h[m][r], two K=16 chunks per 32-m iteration
    a11 = MFMA16K(p00.s, bh1lo, a11, 0, 0, 0);
    a11 = MFMA16K(p01.s, bh1hi, a11, 0, 0, 0);
    a12 = MFMA16K(p00.s, bh2lo, a12, 0, 0, 0);
    a12 = MFMA16K(p01.s, bh2hi, a12, 0, 0, 0);
    a21 = MFMA16K(p10.s, bh1lo, a21, 0, 0, 0);
    a21 = MFMA16K(p11.s, bh1hi, a21, 0, 0, 0);
    a22 = MFMA16K(p10.s, bh2lo, a22, 0, 0, 0);
    a22 = MFMA16K(p11.s, bh2hi, a22, 0, 0, 0);
  }
  // stash y partial for this m-eighth: [wave][token 0..31][r 0..31]
  {
    float* yp = &ylds[wave][0];
#pragma unroll
    for (int r = 0; r < 4; ++r) {
      yp[(q * 4 + r) * 36 + col] = a11[r];
      yp[(q * 4 + r) * 36 + col + 16] = a12[r];
      yp[(16 + q * 4 + r) * 36 + col] = a21[r];
      yp[(16 + q * 4 + r) * 36 + col + 16] = a22[r];
    }
  }
  __syncthreads();
  // epilogue: wave -> (tile = w&1: 16 tokens, hh = w>>1: 64-channel quarter)
  {
    const int tile = wave & 1, hh = wave >> 1;  // hh in 0..3
    float s[8] = {0.f, 0.f, 0.f, 0.f, 0.f, 0.f, 0.f, 0.f};
#pragma unroll
    for (int w2 = 0; w2 < 8; ++w2) {
      const float* yp = &ylds[w2][(tile * 16 + col) * 36 + q * 8];
      const float4 u0 = *(const float4*)yp;
      const float4 u1 = *(const float4*)(yp + 4);
      s[0] += u0.x; s[1] += u0.y; s[2] += u0.z; s[3] += u0.w;
      s[4] += u1.x; s[5] += u1.y; s[6] += u1.z; s[7] += u1.w;
    }
    short8 ay;
#pragma unroll
    for (int j = 0; j < 8; ++j) ay[j] = (short)f2bf(s[j]);
    const float gm = gamma[0];
    float* sc = &sc_all[wave][0];  // per-wave scratch, 16 x 36 floats
    const int row = lane >> 2, c4 = (lane & 3) * 4;
#pragma unroll
    for (int tp = 0; tp < 4; tp += 2) {
      const short8 bw0 = *(const short8*)(wvlds + (hh * 4 + tp) * 512 + lane * 8);
      const short8 bw1 = *(const short8*)(wvlds + (hh * 4 + tp + 1) * 512 + lane * 8);
      const floatx4 d0 = MFMA16(ay, bw0, zero, 0, 0, 0);
      const floatx4 d1 = MFMA16(ay, bw1, zero, 0, 0, 0);
#pragma unroll
      for (int r = 0; r < 4; ++r) {
        sc[(q * 4 + r) * 36 + col] = d0[r];
        sc[(q * 4 + r) * 36 + col + 16] = d1[r];
      }
      // same-wave readback, row-major -> coalesced float4 global I/O
#pragma unroll
      for (int j = 0; j < 2; ++j) {
        const float4 v = *(const float4*)(sc + row * 36 + c4 + j * 16);
        const long gidx = (long)(b * NN + t0 + tile * 16 + row) * CC +
                          hh * 64 + tp * 16 + j * 16 + c4;
        const float4 xv = *(const float4*)(x + gidx);
        float4 o;
        o.x = gm * v.x + xv.x; o.y = gm * v.y + xv.y;
        o.z = gm * v.z + xv.z; o.w = gm * v.w + xv.w;
        *(float4*)(out + gidx) = o;
      }
    }
  }
}

extern "C" void kernel_launch(void* const* d_in, const int* in_sizes, int n_in,
                              void* d_out, int out_size, void* d_ws, size_t ws_size,
                              hipStream_t stream) {
  const float* x = (const float*)d_in[0];
  const float* wf = (const float*)d_in[1];
  const float* wg = (const float*)d_in[2];
  const float* wh = (const float*)d_in[3];
  const float* wv = (const float*)d_in[4];
  const float* gamma = (const float*)d_in[5];
  float* out = (float*)d_out;

  unsigned short* f16 = (unsigned short*)d_ws;           // B*N*R (x LOG2E)
  unsigned short* g16 = f16 + (long)BB * NN * RR;        // B*N*R
  unsigned short* hT16 = g16 + (long)BB * NN * RR;       // B*R*N (m-interleaved)
  float* nlg2cs = (float*)(hT16 + (long)BB * NN * RR);   // B*N softmax bias

  k_fgh<<<BB * NN / 64, 256, 0, stream>>>(x, wf, wg, wh, f16, g16, hT16);
  k_colsum<<<BB * NN / 32, 256, 0, stream>>>(f16, g16, nlg2cs);
  k_pvout<<<BB * 128, 512, 0, stream>>>(f16, g16, hT16, nlg2cs, wv, x, gamma, out);
}

// Round 3
// 126.452 us; speedup vs baseline: 1.0449x; 1.0449x over previous
//
#include <hip/hip_runtime.h>

// SelfAttention2D: B=4, N=4096, C=256, R=32, fp32 in/out.
// out = gamma * ((softmax_axis1(f g^T) h) w_v) + x.
// 4 kernels: k_prep (weight B-frag pack), k_fgh (projections), k_colsum
// (softmax-axis=1 final bias -log2(colsum)), k_pvout (S^T + normalized exp2
// via MFMA C-operand bias + in-register PV + w_v projection + residual).
// f pre-scaled by log2(e) -> raw v_exp. |s|*log2e < 64 so no max pass;
// P = exp2(s' - lg2cs) <= 1.
// R6: grid.sync() ~50us at 512 blocks — block-local fusion only.
// R7: PV chain latency-bound; keep ILP-4/wave.
// R8: scattered b16 LDS packs are conflict-expensive; pack once in k_prep.
// R11: pvout TLP 4 waves/SIMD.
// R12: PV via mfma_f32_16x16x16bf16_1k — A-frag layout == S^T C/D layout, so
// exp2(d)->bfpack feeds PV in-register; P^T LDS round-trip deleted. NEUTRAL.
// R13: 5->3 kernels with per-block weight self-pack REGRESSED (+7us): the
// scattered scalar re-reads of weights per block cost more than 2 launches
// + scaleh saved => launch overhead is small; never replicate packing work.
// R14: restore k_prep; keep bias-normalization (scaleh dead); pvout 64
// tokens/block via 1024-thr blocks (16 waves = 2 token-halves x 8
// m-eighths, inner body identical to R12) => g/hT L2 traffic 256->128 MB.

#define BB 4
#define NN 4096
#define CC 256
#define RR 32
#define LOG2E 1.44269504088896340736f

typedef short short8 __attribute__((ext_vector_type(8)));            // 8 bf16
typedef short short4v __attribute__((ext_vector_type(4)));           // 4 bf16
typedef unsigned short ushort8 __attribute__((ext_vector_type(8)));
typedef float floatx4 __attribute__((ext_vector_type(4)));           // MFMA C/D

#define MFMA16 __builtin_amdgcn_mfma_f32_16x16x32_bf16
#define MFMA16K __builtin_amdgcn_mfma_f32_16x16x16bf16_1k

static __device__ __forceinline__ unsigned short f2bf(float f) {
  union { float f; unsigned u; } v; v.f = f;
  const unsigned r = v.u + 0x7fffu + ((v.u >> 16) & 1u);  // RNE
  return (unsigned short)(r >> 16);
}
// pack trunc-bf16(lo), trunc-bf16(hi) into one uint via v_perm_b32
static __device__ __forceinline__ unsigned bfpack(float lo, float hi) {
  return __builtin_amdgcn_perm(__float_as_uint(hi), __float_as_uint(lo), 0x07060302u);
}

// ------------------------------ k_prep: pack weights into B-frag bf16 layout
__global__ __launch_bounds__(256) void k_prep(
    const float* __restrict__ wf, const float* __restrict__ wg,
    const float* __restrict__ wh, const float* __restrict__ wv,
    unsigned short* __restrict__ wfrag, unsigned short* __restrict__ wvfrag) {
  const int idx = blockIdx.x * 256 + threadIdx.x;  // 0..32767
  const int lane = (idx >> 3) & 63;
  const int j = idx & 7;
  const int col = lane & 15, q = lane >> 4;
  if (idx < 24576) {
    const int mat = idx >> 13;
    const int fid = (idx >> 9) & 15;
    const int kc = fid >> 1, nt = fid & 1;
    const float* w = (mat == 0) ? wf : ((mat == 1) ? wg : wh);
    wfrag[idx] = f2bf(w[(kc * 32 + q * 8 + j) * RR + nt * 16 + col]);
  } else {
    const int r = idx - 24576;
    const int t = (r >> 9) & 15;
    wvfrag[r] = f2bf(wv[(q * 8 + j) * CC + t * 16 + col]);
  }
}

// --------------- k_fgh: f,g,h = x @ {wf,wg,wh}; packed frags staged to LDS
__global__ __launch_bounds__(256) void k_fgh(
    const float* __restrict__ x, const unsigned short* __restrict__ wfrag,
    unsigned short* __restrict__ f16, unsigned short* __restrict__ g16,
    unsigned short* __restrict__ hT16) {
  __shared__ unsigned short wflds[24576];  // 48 KB packed frags
  const int tid = threadIdx.x, lane = tid & 63, wave = tid >> 6;
  const int col = lane & 15, q = lane >> 4;
  {  // conflict-free contiguous stage: 3072 uint4
    const uint4* src = (const uint4*)wfrag;
    uint4* dst = (uint4*)wflds;
#pragma unroll
    for (int i = 0; i < 12; ++i) dst[tid + i * 256] = src[tid + i * 256];
  }
  __syncthreads();
  const int t0 = blockIdx.x * 64 + wave * 16;
  short8 af[8];
  const float* xr = x + (long)(t0 + col) * CC + q * 8;
#pragma unroll
  for (int kc = 0; kc < 8; ++kc) {
    float tmp[8];
    *(float4*)(tmp) = *(const float4*)(xr + kc * 32);
    *(float4*)(tmp + 4) = *(const float4*)(xr + kc * 32 + 4);
    short8 o;
#pragma unroll
    for (int j = 0; j < 8; ++j) o[j] = (short)f2bf(tmp[j]);
    af[kc] = o;
  }
  const floatx4 zero = {0.f, 0.f, 0.f, 0.f};
  floatx4 acc[3][2];
#pragma unroll
  for (int m = 0; m < 3; ++m) { acc[m][0] = zero; acc[m][1] = zero; }
#pragma unroll
  for (int kc = 0; kc < 8; ++kc) {
#pragma unroll
    for (int mat = 0; mat < 3; ++mat) {
#pragma unroll
      for (int nt = 0; nt < 2; ++nt) {
        const short8 bf = *(const short8*)(wflds + (mat * 16 + kc * 2 + nt) * 512 + lane * 8);
        acc[mat][nt] = MFMA16(af[kc], bf, acc[mat][nt], 0, 0, 0);
      }
    }
  }
  const int b = t0 >> 12;
#pragma unroll
  for (int nt = 0; nt < 2; ++nt) {
#pragma unroll
    for (int r = 0; r < 4; ++r) {
      const int tok = t0 + q * 4 + r;
      const int n = nt * 16 + col;
      f16[(long)tok * RR + n] = f2bf(acc[0][nt][r] * LOG2E);
      g16[(long)tok * RR + n] = f2bf(acc[1][nt][r]);
      // hT stored interleaved within each 32-m chunk: logical m = hi*16+qq*4+j
      // lands at s = qq*8 + hi*4 + j (so pvout's short8 @ m0+q*8 yields both
      // K=16 B-frags). Here qq=q, j=r, hi=(tok>>4)&1.
      const int tl = tok & (NN - 1);
      const int sp = (tl & ~31) | (q << 3) | ((tl & 16) >> 2) | r;
      hT16[((long)b * RR + n) * NN + sp] = f2bf(acc[2][nt][r]);
    }
  }
}

// ------- k_colsum: nlg2cs[b][m] = -log2( sum_n exp2(s'[n,m]) )  (final)
// block = 32 m-columns; 4 waves split the n range; LDS cross-wave reduce.
__global__ __launch_bounds__(256) void k_colsum(
    const unsigned short* __restrict__ f16, const unsigned short* __restrict__ g16,
    float* __restrict__ nlg2cs) {
  __shared__ float red[4][32];
  const int tid = threadIdx.x, lane = tid & 63, wave = tid >> 6;
  const int col = lane & 15, q = lane >> 4;
  const int b = blockIdx.x >> 7;
  const int m0 = (blockIdx.x & 127) * 32;
  const short8 bg1 = *(const short8*)(g16 + ((long)(b * NN + m0 + col)) * RR + q * 8);
  const short8 bg2 = *(const short8*)(g16 + ((long)(b * NN + m0 + 16 + col)) * RR + q * 8);
  const floatx4 zero = {0.f, 0.f, 0.f, 0.f};
  float s1 = 0.f, s2 = 0.f;
  const unsigned short* fb = f16 + ((long)b * NN + wave * (NN / 4)) * RR;
#pragma unroll 4
  for (int n = 0; n < NN / 4; n += 16) {
    const short8 af = *(const short8*)(fb + (long)(n + col) * RR + q * 8);
    const floatx4 d1 = MFMA16(af, bg1, zero, 0, 0, 0);
    const floatx4 d2 = MFMA16(af, bg2, zero, 0, 0, 0);
    s1 += __builtin_amdgcn_exp2f(d1[0]) + __builtin_amdgcn_exp2f(d1[1]) +
          __builtin_amdgcn_exp2f(d1[2]) + __builtin_amdgcn_exp2f(d1[3]);
    s2 += __builtin_amdgcn_exp2f(d2[0]) + __builtin_amdgcn_exp2f(d2[1]) +
          __builtin_amdgcn_exp2f(d2[2]) + __builtin_amdgcn_exp2f(d2[3]);
  }
  s1 += __shfl_xor(s1, 16); s1 += __shfl_xor(s1, 32);
  s2 += __shfl_xor(s2, 16); s2 += __shfl_xor(s2, 32);
  if (lane < 16) {
    red[wave][lane] = s1;
    red[wave][lane + 16] = s2;
  }
  __syncthreads();
  if (tid < 32) {
    const float cs = red[0][tid] + red[1][tid] + red[2][tid] + red[3][tid];
    nlg2cs[(long)b * NN + m0 + tid] = -__builtin_amdgcn_logf(cs);
  }
}

// --------- k_pvout: 1024-thread block = 64 tokens; 16 waves = 2 token-halves
// x 8 m-eighths (inner body identical to R12's wave). S^T MFMA with
// C = -lg2cs[m] -> exp2(d) = P in (0,1] already normalized; S^T C/D layout
// IS the 16x16x16 A-frag layout, so PV runs fully in-register.
// 64 tok/block halves per-batch g/hT re-reads (256 -> 128 MB L2 traffic);
// token-half wave pairs share g/hT rows via L1. 1 block/CU, 4 waves/SIMD.
__global__ __launch_bounds__(1024, 4) void k_pvout(
    const unsigned short* __restrict__ f16, const unsigned short* __restrict__ g16,
    const unsigned short* __restrict__ hT16, const float* __restrict__ nlg2cs,
    const unsigned short* __restrict__ wvfrag, const float* __restrict__ x,
    const float* __restrict__ gamma, float* __restrict__ out) {
  __shared__ float ylds[8][64 * 36];     // 72 KB: per-m-eighth y partials
  __shared__ float sc_all[16][16 * 36];  // 36 KB: epilogue store-swizzle scratch
  const int tid = threadIdx.x, lane = tid & 63, wave = tid >> 6;  // 0..15
  const int col = lane & 15, q = lane >> 4;
  const int b = blockIdx.x >> 6;
  const int t0 = (blockIdx.x & 63) * 64;   // token base (in-batch), 64 tokens
  const int tokh = wave & 1, mq = wave >> 1;  // token half, m-eighth
  const int tw = t0 + tokh * 32;
  const floatx4 zero = {0.f, 0.f, 0.f, 0.f};
  // B-frags of S^T: f rows for this wave's 32 tokens (loop-invariant)
  const short8 af1 = *(const short8*)(f16 + ((long)(b * NN + tw + col)) * RR + q * 8);
  const short8 af2 = *(const short8*)(f16 + ((long)(b * NN + tw + 16 + col)) * RR + q * 8);
  floatx4 a11 = zero, a12 = zero, a21 = zero, a22 = zero;
  const unsigned short* gb = g16 + (long)b * NN * RR;
  const unsigned short* hb = hT16 + (long)b * RR * NN;
  const float* csb = nlg2cs + (long)b * NN;
  const int mqb = mq * 512;  // this wave's m-eighth
#pragma unroll 2
  for (int mi = 0; mi < 512; mi += 32) {
    const int m0 = mqb + mi;
    const short8 bg1 = *(const short8*)(gb + (long)(m0 + col) * RR + q * 8);
    const short8 bg2 = *(const short8*)(gb + (long)(m0 + 16 + col) * RR + q * 8);
    // interleaved hT: elements 0..3 = h[m0+q*4+j][r], 4..7 = h[m0+16+q*4+j][r]
    const short8 hv1 = *(const short8*)(hb + (long)col * NN + m0 + q * 8);
    const short8 hv2 = *(const short8*)(hb + (long)(col + 16) * NN + m0 + q * 8);
    // softmax bias as MFMA C-operand: lane reg r <-> m = m0 + q*4 + r
    const floatx4 cm0 = *(const floatx4*)(csb + m0 + q * 4);
    const floatx4 cm1 = *(const floatx4*)(csb + m0 + 16 + q * 4);
    // S^T + bias: A=g(m rows), B=f(n cols) -> lane: s'[n=col][m=m0+q*4+r]-lg2cs
    const floatx4 d00 = MFMA16(bg1, af1, cm0, 0, 0, 0);  // n-blk 0,  m-blk 0
    const floatx4 d01 = MFMA16(bg2, af1, cm1, 0, 0, 0);  // n-blk 0,  m-blk 16
    const floatx4 d10 = MFMA16(bg1, af2, cm0, 0, 0, 0);  // n-blk 16, m-blk 0
    const floatx4 d11 = MFMA16(bg2, af2, cm1, 0, 0, 0);  // n-blk 16, m-blk 16
    // P = exp2(d) in (0,1], packed in-register as 16x16x16 A-frags (k=q*4+j)
    union PU { unsigned u[2]; short4v s; } p00, p01, p10, p11;
    p00.u[0] = bfpack(__builtin_amdgcn_exp2f(d00[0]), __builtin_amdgcn_exp2f(d00[1]));
    p00.u[1] = bfpack(__builtin_amdgcn_exp2f(d00[2]), __builtin_amdgcn_exp2f(d00[3]));
    p01.u[0] = bfpack(__builtin_amdgcn_exp2f(d01[0]), __builtin_amdgcn_exp2f(d01[1]));
    p01.u[1] = bfpack(__builtin_amdgcn_exp2f(d01[2]), __builtin_amdgcn_exp2f(d01[3]));
    p10.u[0] = bfpack(__builtin_amdgcn_exp2f(d10[0]), __builtin_amdgcn_exp2f(d10[1]));
    p10.u[1] = bfpack(__builtin_amdgcn_exp2f(d10[2]), __builtin_amdgcn_exp2f(d10[3]));
    p11.u[0] = bfpack(__builtin_amdgcn_exp2f(d11[0]), __builtin_amdgcn_exp2f(d11[1]));
    p11.u[1] = bfpack(__builtin_amdgcn_exp2f(d11[2]), __builtin_amdgcn_exp2f(d11[3]));
    const short4v bh1lo = __builtin_shufflevector(hv1, hv1, 0, 1, 2, 3);
    const short4v bh1hi = __builtin_shufflevector(hv1, hv1, 4, 5, 6, 7);
    const short4v bh2lo = __builtin_shufflevector(hv2, hv2, 0, 1, 2, 3);
    const short4v bh2hi = __builtin_shufflevector(hv2, hv2, 4, 5, 6, 7);
    // PV: y[n][r] += P[n][m] h[m][r], two K=16 chunks per 32-m iteration
    a11 = MFMA16K(p00.s, bh1lo, a11, 0, 0, 0);
    a11 = MFMA16K(p01.s, bh1hi, a11, 0, 0, 0);
    a12 = MFMA16K(p00.s, bh2lo, a12, 0, 0, 0);
    a12 = MFMA16K(p01.s, bh2hi, a12, 0, 0, 0);
    a21 = MFMA16K(p10.s, bh1lo, a21, 0, 0, 0);
    a21 = MFMA16K(p11.s, bh1hi, a21, 0, 0, 0);
    a22 = MFMA16K(p10.s, bh2lo, a22, 0, 0, 0);
    a22 = MFMA16K(p11.s, bh2hi, a22, 0, 0, 0);
  }
  // stash y partial for this m-eighth: [mq][token 0..63][r 0..31]
  {
    float* yp = &ylds[mq][(tokh * 32) * 36];
#pragma unroll
    for (int r = 0; r < 4; ++r) {
      yp[(q * 4 + r) * 36 + col] = a11[r];
      yp[(q * 4 + r) * 36 + col + 16] = a12[r];
      yp[(16 + q * 4 + r) * 36 + col] = a21[r];
      yp[(16 + q * 4 + r) * 36 + col + 16] = a22[r];
    }
  }
  __syncthreads();
  // epilogue: wave -> (tile = w&3: 16 tokens, hh = w>>2: 64-channel quarter)
  {
    const int tile = wave & 3, hh = wave >> 2;  // tile 0..3, hh 0..3
    float s[8] = {0.f, 0.f, 0.f, 0.f, 0.f, 0.f, 0.f, 0.f};
#pragma unroll
    for (int w2 = 0; w2 < 8; ++w2) {
      const float* yp = &ylds[w2][(tile * 16 + col) * 36 + q * 8];
      const float4 u0 = *(const float4*)yp;
      const float4 u1 = *(const float4*)(yp + 4);
      s[0] += u0.x; s[1] += u0.y; s[2] += u0.z; s[3] += u0.w;
      s[4] += u1.x; s[5] += u1.y; s[6] += u1.z; s[7] += u1.w;
    }
    short8 ay;
#pragma unroll
    for (int j = 0; j < 8; ++j) ay[j] = (short)f2bf(s[j]);
    const float gm = gamma[0];
    float* sc = &sc_all[wave][0];  // per-wave scratch, 16 x 36 floats
    const int row = lane >> 2, c4 = (lane & 3) * 4;
#pragma unroll
    for (int tp = 0; tp < 4; tp += 2) {
      const short8 bw0 = *(const short8*)(wvfrag + (hh * 4 + tp) * 512 + lane * 8);
      const short8 bw1 = *(const short8*)(wvfrag + (hh * 4 + tp + 1) * 512 + lane * 8);
      const floatx4 d0 = MFMA16(ay, bw0, zero, 0, 0, 0);
      const floatx4 d1 = MFMA16(ay, bw1, zero, 0, 0, 0);
#pragma unroll
      for (int r = 0; r < 4; ++r) {
        sc[(q * 4 + r) * 36 + col] = d0[r];
        sc[(q * 4 + r) * 36 + col + 16] = d1[r];
      }
      // same-wave readback, row-major -> coalesced float4 global I/O
#pragma unroll
      for (int j = 0; j < 2; ++j) {
        const float4 v = *(const float4*)(sc + row * 36 + c4 + j * 16);
        const long gidx = (long)(b * NN + t0 + tile * 16 + row) * CC +
                          hh * 64 + tp * 16 + j * 16 + c4;
        const float4 xv = *(const float4*)(x + gidx);
        float4 o;
        o.x = gm * v.x + xv.x; o.y = gm * v.y + xv.y;
        o.z = gm * v.z + xv.z; o.w = gm * v.w + xv.w;
        *(float4*)(out + gidx) = o;
      }
    }
  }
}

extern "C" void kernel_launch(void* const* d_in, const int* in_sizes, int n_in,
                              void* d_out, int out_size, void* d_ws, size_t ws_size,
                              hipStream_t stream) {
  const float* x = (const float*)d_in[0];
  const float* wf = (const float*)d_in[1];
  const float* wg = (const float*)d_in[2];
  const float* wh = (const float*)d_in[3];
  const float* wv = (const float*)d_in[4];
  const float* gamma = (const float*)d_in[5];
  float* out = (float*)d_out;

  unsigned short* f16 = (unsigned short*)d_ws;           // B*N*R (x LOG2E)
  unsigned short* g16 = f16 + (long)BB * NN * RR;        // B*N*R
  unsigned short* hT16 = g16 + (long)BB * NN * RR;       // B*R*N (m-interleaved)
  unsigned short* wfrag = hT16 + (long)BB * NN * RR;     // 24576
  unsigned short* wvfrag = wfrag + 24576;                // 8192
  float* nlg2cs = (float*)(wvfrag + 8192);               // B*N softmax bias

  k_prep<<<128, 256, 0, stream>>>(wf, wg, wh, wv, wfrag, wvfrag);
  k_fgh<<<BB * NN / 64, 256, 0, stream>>>(x, wfrag, f16, g16, hT16);
  k_colsum<<<BB * NN / 32, 256, 0, stream>>>(f16, g16, nlg2cs);
  k_pvout<<<BB * 64, 1024, 0, stream>>>(f16, g16, hT16, nlg2cs, wvfrag, x, gamma, out);
}

// Round 4
// 121.182 us; speedup vs baseline: 1.0904x; 1.0435x over previous
//
#include <hip/hip_runtime.h>

// SelfAttention2D: B=4, N=4096, C=256, R=32, fp32 in/out.
// out = gamma * ((softmax_axis1(f g^T) h) w_v) + x.
// 4 kernels: k_prep (weight B-frag pack), k_fgh (projections), k_colsum
// (softmax-axis=1 partial colsums, high-TLP), k_pvout (bias precompute +
// S^T + normalized exp2 via MFMA C-operand bias + in-register PV + w_v
// projection + residual).
// f pre-scaled by log2(e) -> raw v_exp. |s|*log2e < 64 so no max pass;
// P = exp2(s' - lg2cs) <= 1.
// R6: grid.sync() ~50us at 512 blocks — block-local fusion only.
// R8: scattered b16 LDS packs are conflict-expensive; pack once in k_prep.
// R12: PV via mfma_f32_16x16x16bf16_1k — A-frag layout == S^T C/D layout, so
// exp2(d)->bfpack feeds PV in-register; P^T LDS round-trip deleted. NEUTRAL.
// R13: 5->3 kernels w/ per-block weight self-pack REGRESSED (+7us): launch
// overhead is small; never replicate packing work per block.
// R14: pvout 64tok/block (halved L2 traffic): NEUTRAL-to-worse => pvout not
// L2-BW-bound. Revert to 512-thr/32-tok geometry.
// R15: three structural levers (latency chain R12, launches R13, L2 BW R14)
// all neutral; bottom-up model says kernels sum ~30-45us vs 123 measured.
// Last untested lever: colsum occupancy (was 2 waves/SIMD). CSEG=4 n-split
// -> 2048 blocks (8 waves/SIMD); psum partials; Σseg + -log2 folded into a
// one-time 16KB LDS bias table in pvout's prologue (replaces per-iter
// global cm loads). If neutral => fixed-tax hypothesis confirmed; kernels
// are at their floor.

#define BB 4
#define NN 4096
#define CC 256
#define RR 32
#define CSEG 4   // n-split for colsum
#define LOG2E 1.44269504088896340736f

typedef short short8 __attribute__((ext_vector_type(8)));            // 8 bf16
typedef short short4v __attribute__((ext_vector_type(4)));           // 4 bf16
typedef unsigned short ushort8 __attribute__((ext_vector_type(8)));
typedef float floatx4 __attribute__((ext_vector_type(4)));           // MFMA C/D

#define MFMA16 __builtin_amdgcn_mfma_f32_16x16x32_bf16
#define MFMA16K __builtin_amdgcn_mfma_f32_16x16x16bf16_1k

static __device__ __forceinline__ unsigned short f2bf(float f) {
  union { float f; unsigned u; } v; v.f = f;
  const unsigned r = v.u + 0x7fffu + ((v.u >> 16) & 1u);  // RNE
  return (unsigned short)(r >> 16);
}
// pack trunc-bf16(lo), trunc-bf16(hi) into one uint via v_perm_b32
static __device__ __forceinline__ unsigned bfpack(float lo, float hi) {
  return __builtin_amdgcn_perm(__float_as_uint(hi), __float_as_uint(lo), 0x07060302u);
}

// ------------------------------ k_prep: pack weights into B-frag bf16 layout
__global__ __launch_bounds__(256) void k_prep(
    const float* __restrict__ wf, const float* __restrict__ wg,
    const float* __restrict__ wh, const float* __restrict__ wv,
    unsigned short* __restrict__ wfrag, unsigned short* __restrict__ wvfrag) {
  const int idx = blockIdx.x * 256 + threadIdx.x;  // 0..32767
  const int lane = (idx >> 3) & 63;
  const int j = idx & 7;
  const int col = lane & 15, q = lane >> 4;
  if (idx < 24576) {
    const int mat = idx >> 13;
    const int fid = (idx >> 9) & 15;
    const int kc = fid >> 1, nt = fid & 1;
    const float* w = (mat == 0) ? wf : ((mat == 1) ? wg : wh);
    wfrag[idx] = f2bf(w[(kc * 32 + q * 8 + j) * RR + nt * 16 + col]);
  } else {
    const int r = idx - 24576;
    const int t = (r >> 9) & 15;
    wvfrag[r] = f2bf(wv[(q * 8 + j) * CC + t * 16 + col]);
  }
}

// --------------- k_fgh: f,g,h = x @ {wf,wg,wh}; packed frags staged to LDS
__global__ __launch_bounds__(256) void k_fgh(
    const float* __restrict__ x, const unsigned short* __restrict__ wfrag,
    unsigned short* __restrict__ f16, unsigned short* __restrict__ g16,
    unsigned short* __restrict__ hT16) {
  __shared__ unsigned short wflds[24576];  // 48 KB packed frags
  const int tid = threadIdx.x, lane = tid & 63, wave = tid >> 6;
  const int col = lane & 15, q = lane >> 4;
  {  // conflict-free contiguous stage: 3072 uint4
    const uint4* src = (const uint4*)wfrag;
    uint4* dst = (uint4*)wflds;
#pragma unroll
    for (int i = 0; i < 12; ++i) dst[tid + i * 256] = src[tid + i * 256];
  }
  __syncthreads();
  const int t0 = blockIdx.x * 64 + wave * 16;
  short8 af[8];
  const float* xr = x + (long)(t0 + col) * CC + q * 8;
#pragma unroll
  for (int kc = 0; kc < 8; ++kc) {
    float tmp[8];
    *(float4*)(tmp) = *(const float4*)(xr + kc * 32);
    *(float4*)(tmp + 4) = *(const float4*)(xr + kc * 32 + 4);
    short8 o;
#pragma unroll
    for (int j = 0; j < 8; ++j) o[j] = (short)f2bf(tmp[j]);
    af[kc] = o;
  }
  const floatx4 zero = {0.f, 0.f, 0.f, 0.f};
  floatx4 acc[3][2];
#pragma unroll
  for (int m = 0; m < 3; ++m) { acc[m][0] = zero; acc[m][1] = zero; }
#pragma unroll
  for (int kc = 0; kc < 8; ++kc) {
#pragma unroll
    for (int mat = 0; mat < 3; ++mat) {
#pragma unroll
      for (int nt = 0; nt < 2; ++nt) {
        const short8 bf = *(const short8*)(wflds + (mat * 16 + kc * 2 + nt) * 512 + lane * 8);
        acc[mat][nt] = MFMA16(af[kc], bf, acc[mat][nt], 0, 0, 0);
      }
    }
  }
  const int b = t0 >> 12;
#pragma unroll
  for (int nt = 0; nt < 2; ++nt) {
#pragma unroll
    for (int r = 0; r < 4; ++r) {
      const int tok = t0 + q * 4 + r;
      const int n = nt * 16 + col;
      f16[(long)tok * RR + n] = f2bf(acc[0][nt][r] * LOG2E);
      g16[(long)tok * RR + n] = f2bf(acc[1][nt][r]);
      // hT stored interleaved within each 32-m chunk: logical m = hi*16+qq*4+j
      // lands at s = qq*8 + hi*4 + j (so pvout's short8 @ m0+q*8 yields both
      // K=16 B-frags). Here qq=q, j=r, hi=(tok>>4)&1.
      const int tl = tok & (NN - 1);
      const int sp = (tl & ~31) | (q << 3) | ((tl & 16) >> 2) | r;
      hT16[((long)b * RR + n) * NN + sp] = f2bf(acc[2][nt][r]);
    }
  }
}

// --------------------- k_colsum: psum[seg][b][m] = sum_{n in seg} exp2(s'[n,m])
// 2048 blocks (8/CU, 8 waves/SIMD): block = (seg, b, 32-m); 4 waves split the
// seg's n-range (16 iters/wave); LDS cross-wave reduce; raw partials (no log).
__global__ __launch_bounds__(256) void k_colsum(
    const unsigned short* __restrict__ f16, const unsigned short* __restrict__ g16,
    float* __restrict__ psum) {
  __shared__ float red[4][32];
  const int tid = threadIdx.x, lane = tid & 63, wave = tid >> 6;
  const int col = lane & 15, q = lane >> 4;
  const int mblk = blockIdx.x & 127;
  const int b = (blockIdx.x >> 7) & 3;
  const int seg = blockIdx.x >> 9;
  const int m0 = mblk * 32;
  const short8 bg1 = *(const short8*)(g16 + ((long)(b * NN + m0 + col)) * RR + q * 8);
  const short8 bg2 = *(const short8*)(g16 + ((long)(b * NN + m0 + 16 + col)) * RR + q * 8);
  const floatx4 zero = {0.f, 0.f, 0.f, 0.f};
  float s1 = 0.f, s2 = 0.f;
  const unsigned short* fb =
      f16 + ((long)b * NN + seg * (NN / CSEG) + wave * (NN / CSEG / 4)) * RR;
#pragma unroll 4
  for (int n = 0; n < NN / CSEG / 4; n += 16) {
    const short8 af = *(const short8*)(fb + (long)(n + col) * RR + q * 8);
    const floatx4 d1 = MFMA16(af, bg1, zero, 0, 0, 0);
    const floatx4 d2 = MFMA16(af, bg2, zero, 0, 0, 0);
    s1 += __builtin_amdgcn_exp2f(d1[0]) + __builtin_amdgcn_exp2f(d1[1]) +
          __builtin_amdgcn_exp2f(d1[2]) + __builtin_amdgcn_exp2f(d1[3]);
    s2 += __builtin_amdgcn_exp2f(d2[0]) + __builtin_amdgcn_exp2f(d2[1]) +
          __builtin_amdgcn_exp2f(d2[2]) + __builtin_amdgcn_exp2f(d2[3]);
  }
  s1 += __shfl_xor(s1, 16); s1 += __shfl_xor(s1, 32);
  s2 += __shfl_xor(s2, 16); s2 += __shfl_xor(s2, 32);
  if (lane < 16) {
    red[wave][lane] = s1;
    red[wave][lane + 16] = s2;
  }
  __syncthreads();
  if (tid < 32) {
    psum[(long)seg * (BB * NN) + b * NN + m0 + tid] =
        red[0][tid] + red[1][tid] + red[2][tid] + red[3][tid];
  }
}

// --------- k_pvout: 512-thread block = 32 tokens; 8 waves = m-eighths.
// Prologue: bias[m] = -log2(sum_seg psum[seg][b][m]) into 16 KB LDS (once).
// S^T MFMA with C = bias[m] -> exp2(d) = P in (0,1] already normalized;
// S^T C/D layout IS the 16x16x16 A-frag layout, so PV runs in-register.
__global__ __launch_bounds__(512, 4) void k_pvout(
    const unsigned short* __restrict__ f16, const unsigned short* __restrict__ g16,
    const unsigned short* __restrict__ hT16, const float* __restrict__ psum,
    const unsigned short* __restrict__ wvfrag, const float* __restrict__ x,
    const float* __restrict__ gamma, float* __restrict__ out) {
  __shared__ float ylds[8][32 * 36];    // 36 KB: per-wave y partials
  __shared__ float sc_all[8][16 * 36];  // 18 KB: epilogue store-swizzle scratch
  __shared__ float bias[NN];            // 16 KB: -log2(colsum) per m
  const int tid = threadIdx.x, lane = tid & 63, wave = tid >> 6;  // 0..7
  const int col = lane & 15, q = lane >> 4;
  const int b = blockIdx.x >> 7;
  const int t0 = (blockIdx.x & 127) * 32;  // token base (in-batch), 32 tokens
  const floatx4 zero = {0.f, 0.f, 0.f, 0.f};
  {  // bias prologue: thread t -> m = t*8..t*8+7 (coalesced float4 loads)
    float cs[8] = {0.f, 0.f, 0.f, 0.f, 0.f, 0.f, 0.f, 0.f};
#pragma unroll
    for (int sg = 0; sg < CSEG; ++sg) {
      const float* p = psum + (long)sg * (BB * NN) + b * NN + tid * 8;
      const float4 a = *(const float4*)p;
      const float4 c = *(const float4*)(p + 4);
      cs[0] += a.x; cs[1] += a.y; cs[2] += a.z; cs[3] += a.w;
      cs[4] += c.x; cs[5] += c.y; cs[6] += c.z; cs[7] += c.w;
    }
#pragma unroll
    for (int j = 0; j < 8; ++j) bias[tid * 8 + j] = -__builtin_amdgcn_logf(cs[j]);
  }
  // B-frags of S^T: f rows for the block's 32 tokens (loop-invariant)
  const short8 af1 = *(const short8*)(f16 + ((long)(b * NN + t0 + col)) * RR + q * 8);
  const short8 af2 = *(const short8*)(f16 + ((long)(b * NN + t0 + 16 + col)) * RR + q * 8);
  floatx4 a11 = zero, a12 = zero, a21 = zero, a22 = zero;
  const unsigned short* gb = g16 + (long)b * NN * RR;
  const unsigned short* hb = hT16 + (long)b * RR * NN;
  const int mq = wave * 512;  // this wave's m-eighth
  __syncthreads();            // bias table ready
#pragma unroll 2
  for (int mi = 0; mi < 512; mi += 32) {
    const int m0 = mq + mi;
    const short8 bg1 = *(const short8*)(gb + (long)(m0 + col) * RR + q * 8);
    const short8 bg2 = *(const short8*)(gb + (long)(m0 + 16 + col) * RR + q * 8);
    // interleaved hT: elements 0..3 = h[m0+q*4+j][r], 4..7 = h[m0+16+q*4+j][r]
    const short8 hv1 = *(const short8*)(hb + (long)col * NN + m0 + q * 8);
    const short8 hv2 = *(const short8*)(hb + (long)(col + 16) * NN + m0 + q * 8);
    // softmax bias as MFMA C-operand from LDS: lane reg r <-> m = m0 + q*4 + r
    const floatx4 cm0 = *(const floatx4*)(bias + m0 + q * 4);
    const floatx4 cm1 = *(const floatx4*)(bias + m0 + 16 + q * 4);
    // S^T + bias: A=g(m rows), B=f(n cols) -> lane: s'[n=col][m=m0+q*4+r]-lg2cs
    const floatx4 d00 = MFMA16(bg1, af1, cm0, 0, 0, 0);  // n-blk 0,  m-blk 0
    const floatx4 d01 = MFMA16(bg2, af1, cm1, 0, 0, 0);  // n-blk 0,  m-blk 16
    const floatx4 d10 = MFMA16(bg1, af2, cm0, 0, 0, 0);  // n-blk 16, m-blk 0
    const floatx4 d11 = MFMA16(bg2, af2, cm1, 0, 0, 0);  // n-blk 16, m-blk 16
    // P = exp2(d) in (0,1], packed in-register as 16x16x16 A-frags (k=q*4+j)
    union PU { unsigned u[2]; short4v s; } p00, p01, p10, p11;
    p00.u[0] = bfpack(__builtin_amdgcn_exp2f(d00[0]), __builtin_amdgcn_exp2f(d00[1]));
    p00.u[1] = bfpack(__builtin_amdgcn_exp2f(d00[2]), __builtin_amdgcn_exp2f(d00[3]));
    p01.u[0] = bfpack(__builtin_amdgcn_exp2f(d01[0]), __builtin_amdgcn_exp2f(d01[1]));
    p01.u[1] = bfpack(__builtin_amdgcn_exp2f(d01[2]), __builtin_amdgcn_exp2f(d01[3]));
    p10.u[0] = bfpack(__builtin_amdgcn_exp2f(d10[0]), __builtin_amdgcn_exp2f(d10[1]));
    p10.u[1] = bfpack(__builtin_amdgcn_exp2f(d10[2]), __builtin_amdgcn_exp2f(d10[3]));
    p11.u[0] = bfpack(__builtin_amdgcn_exp2f(d11[0]), __builtin_amdgcn_exp2f(d11[1]));
    p11.u[1] = bfpack(__builtin_amdgcn_exp2f(d11[2]), __builtin_amdgcn_exp2f(d11[3]));
    const short4v bh1lo = __builtin_shufflevector(hv1, hv1, 0, 1, 2, 3);
    const short4v bh1hi = __builtin_shufflevector(hv1, hv1, 4, 5, 6, 7);
    const short4v bh2lo = __builtin_shufflevector(hv2, hv2, 0, 1, 2, 3);
    const short4v bh2hi = __builtin_shufflevector(hv2, hv2, 4, 5, 6, 7);
    // PV: y[n][r] += P[n][m] h[m][r], two K=16 chunks per 32-m iteration
    a11 = MFMA16K(p00.s, bh1lo, a11, 0, 0, 0);
    a11 = MFMA16K(p01.s, bh1hi, a11, 0, 0, 0);
    a12 = MFMA16K(p00.s, bh2lo, a12, 0, 0, 0);
    a12 = MFMA16K(p01.s, bh2hi, a12, 0, 0, 0);
    a21 = MFMA16K(p10.s, bh1lo, a21, 0, 0, 0);
    a21 = MFMA16K(p11.s, bh1hi, a21, 0, 0, 0);
    a22 = MFMA16K(p10.s, bh2lo, a22, 0, 0, 0);
    a22 = MFMA16K(p11.s, bh2hi, a22, 0, 0, 0);
  }
  // stash y partial for this m-eighth: [wave][token 0..31][r 0..31]
  {
    float* yp = &ylds[wave][0];
#pragma unroll
    for (int r = 0; r < 4; ++r) {
      yp[(q * 4 + r) * 36 + col] = a11[r];
      yp[(q * 4 + r) * 36 + col + 16] = a12[r];
      yp[(16 + q * 4 + r) * 36 + col] = a21[r];
      yp[(16 + q * 4 + r) * 36 + col + 16] = a22[r];
    }
  }
  __syncthreads();
  // epilogue: wave -> (tile = w&1: 16 tokens, hh = w>>1: 64-channel quarter)
  {
    const int tile = wave & 1, hh = wave >> 1;  // hh in 0..3
    float s[8] = {0.f, 0.f, 0.f, 0.f, 0.f, 0.f, 0.f, 0.f};
#pragma unroll
    for (int w2 = 0; w2 < 8; ++w2) {
      const float* yp = &ylds[w2][(tile * 16 + col) * 36 + q * 8];
      const float4 u0 = *(const float4*)yp;
      const float4 u1 = *(const float4*)(yp + 4);
      s[0] += u0.x; s[1] += u0.y; s[2] += u0.z; s[3] += u0.w;
      s[4] += u1.x; s[5] += u1.y; s[6] += u1.z; s[7] += u1.w;
    }
    short8 ay;
#pragma unroll
    for (int j = 0; j < 8; ++j) ay[j] = (short)f2bf(s[j]);
    const float gm = gamma[0];
    float* sc = &sc_all[wave][0];  // per-wave scratch, 16 x 36 floats
    const int row = lane >> 2, c4 = (lane & 3) * 4;
#pragma unroll
    for (int tp = 0; tp < 4; tp += 2) {
      const short8 bw0 = *(const short8*)(wvfrag + (hh * 4 + tp) * 512 + lane * 8);
      const short8 bw1 = *(const short8*)(wvfrag + (hh * 4 + tp + 1) * 512 + lane * 8);
      const floatx4 d0 = MFMA16(ay, bw0, zero, 0, 0, 0);
      const floatx4 d1 = MFMA16(ay, bw1, zero, 0, 0, 0);
#pragma unroll
      for (int r = 0; r < 4; ++r) {
        sc[(q * 4 + r) * 36 + col] = d0[r];
        sc[(q * 4 + r) * 36 + col + 16] = d1[r];
      }
      // same-wave readback, row-major -> coalesced float4 global I/O
#pragma unroll
      for (int j = 0; j < 2; ++j) {
        const float4 v = *(const float4*)(sc + row * 36 + c4 + j * 16);
        const long gidx = (long)(b * NN + t0 + tile * 16 + row) * CC +
                          hh * 64 + tp * 16 + j * 16 + c4;
        const float4 xv = *(const float4*)(x + gidx);
        float4 o;
        o.x = gm * v.x + xv.x; o.y = gm * v.y + xv.y;
        o.z = gm * v.z + xv.z; o.w = gm * v.w + xv.w;
        *(float4*)(out + gidx) = o;
      }
    }
  }
}

extern "C" void kernel_launch(void* const* d_in, const int* in_sizes, int n_in,
                              void* d_out, int out_size, void* d_ws, size_t ws_size,
                              hipStream_t stream) {
  const float* x = (const float*)d_in[0];
  const float* wf = (const float*)d_in[1];
  const float* wg = (const float*)d_in[2];
  const float* wh = (const float*)d_in[3];
  const float* wv = (const float*)d_in[4];
  const float* gamma = (const float*)d_in[5];
  float* out = (float*)d_out;

  unsigned short* f16 = (unsigned short*)d_ws;           // B*N*R (x LOG2E)
  unsigned short* g16 = f16 + (long)BB * NN * RR;        // B*N*R
  unsigned short* hT16 = g16 + (long)BB * NN * RR;       // B*R*N (m-interleaved)
  unsigned short* wfrag = hT16 + (long)BB * NN * RR;     // 24576
  unsigned short* wvfrag = wfrag + 24576;                // 8192
  float* psum = (float*)(wvfrag + 8192);                 // CSEG*B*N partials

  k_prep<<<128, 256, 0, stream>>>(wf, wg, wh, wv, wfrag, wvfrag);
  k_fgh<<<BB * NN / 64, 256, 0, stream>>>(x, wfrag, f16, g16, hT16);
  k_colsum<<<CSEG * BB * 128, 256, 0, stream>>>(f16, g16, psum);
  k_pvout<<<BB * 128, 512, 0, stream>>>(f16, g16, hT16, psum, wvfrag, x, gamma, out);
}

// Round 5
// 119.681 us; speedup vs baseline: 1.1041x; 1.0125x over previous
//
#include <hip/hip_runtime.h>

// SelfAttention2D: B=4, N=4096, C=256, R=32, fp32 in/out.
// out = gamma * ((softmax_axis1(f g^T) h) w_v) + x.
// 3 kernels: k_fgh (weight pack from global + projections), k_colsum
// (softmax-axis=1 partial colsums, 8 waves/SIMD), k_pvout (bias precompute +
// S^T + normalized exp2 via MFMA C-operand bias + in-register PV + w_v
// projection + residual).
// f pre-scaled by log2(e) -> raw v_exp. |s|*log2e < 64 so no max pass;
// P = exp2(s' - lg2cs) <= 1.
// R6: grid.sync() ~50us at 512 blocks — block-local fusion only.
// R12: PV via mfma_f32_16x16x16bf16_1k — A-frag layout == S^T C/D layout, so
// exp2(d)->bfpack feeds PV in-register; P^T LDS round-trip deleted. NEUTRAL.
// R13: 5->3 merge with SCALAR scattered per-block weight re-reads REGRESSED
// (+7us) — confounded test of launch overhead.
// R14: pvout 64tok/block (halved L2 traffic): NEUTRAL => not L2-BW-bound.
// R15: colsum TLP 2->8 waves/SIMD: -5.3us (best). Occupancy/latency exposure
// is real. psum partials + one-time LDS bias table in pvout prologue.
// R16: clean boundary test — k_prep folded into k_fgh via COALESCED float4
// weight reads + one-time scattered b16 LDS writes (inverse of prep's map;
// ~1us total, unlike R13's scalar version). wvfrag written by fgh blocks
// 0..31. colsum/pvout byte-identical to R15. 4->3 launches.

#define BB 4
#define NN 4096
#define CC 256
#define RR 32
#define CSEG 4   // n-split for colsum
#define LOG2E 1.44269504088896340736f

typedef short short8 __attribute__((ext_vector_type(8)));            // 8 bf16
typedef short short4v __attribute__((ext_vector_type(4)));           // 4 bf16
typedef unsigned short ushort8 __attribute__((ext_vector_type(8)));
typedef float floatx4 __attribute__((ext_vector_type(4)));           // MFMA C/D

#define MFMA16 __builtin_amdgcn_mfma_f32_16x16x32_bf16
#define MFMA16K __builtin_amdgcn_mfma_f32_16x16x16bf16_1k

static __device__ __forceinline__ unsigned short f2bf(float f) {
  union { float f; unsigned u; } v; v.f = f;
  const unsigned r = v.u + 0x7fffu + ((v.u >> 16) & 1u);  // RNE
  return (unsigned short)(r >> 16);
}
// pack trunc-bf16(lo), trunc-bf16(hi) into one uint via v_perm_b32
static __device__ __forceinline__ unsigned bfpack(float lo, float hi) {
  return __builtin_amdgcn_perm(__float_as_uint(hi), __float_as_uint(lo), 0x07060302u);
}

// --------------- k_fgh: f,g,h = x @ {wf,wg,wh}; weights packed in-block via
// coalesced float4 reads (L2-resident) + one-time scattered b16 LDS writes.
// Blocks 0..31 also emit wvfrag (global) for pvout's epilogue.
__global__ __launch_bounds__(256) void k_fgh(
    const float* __restrict__ x, const float* __restrict__ wf,
    const float* __restrict__ wg, const float* __restrict__ wh,
    const float* __restrict__ wv, unsigned short* __restrict__ f16,
    unsigned short* __restrict__ g16, unsigned short* __restrict__ hT16,
    unsigned short* __restrict__ wvfrag) {
  __shared__ unsigned short wflds[24576];  // 48 KB packed frags
  const int tid = threadIdx.x, lane = tid & 63, wave = tid >> 6;
  const int col = lane & 15, q = lane >> 4;
  {  // weight pack: inverse of old k_prep's map. Element (k,n) of mat ->
     // wflds[mat*8192 + ((k>>5)*2 + (n>>4))*512 + (((k>>3)&3)*16 + (n&15))*8
     //       + (k&7)]. Reads are linear float4 (fully coalesced).
    const float* mats[3] = {wf, wg, wh};
#pragma unroll
    for (int mat = 0; mat < 3; ++mat) {
      const float* w = mats[mat];
#pragma unroll
      for (int rnd = 0; rnd < 8; ++rnd) {
        const int e = rnd * 1024 + tid * 4;  // element index within mat
        const float4 v = *(const float4*)(w + e);
        const int k = e >> 5;     // RR = 32 elems per row
        const int n0 = e & 31;    // n0 % 4 == 0, same nt for all 4
        const int base = mat * 8192 + (((k >> 3) & 3) * 16) * 8 + (k & 7) +
                         (k >> 5) * 1024;
        const float vv[4] = {v.x, v.y, v.z, v.w};
#pragma unroll
        for (int t = 0; t < 4; ++t) {
          const int n = n0 + t;
          wflds[base + (n >> 4) * 512 + (n & 15) * 8] = f2bf(vv[t]);
        }
      }
    }
    if (blockIdx.x < 32) {  // wvfrag pack (same map as old k_prep)
      const int idx = blockIdx.x * 256 + tid;  // 0..8191
      const int t = (idx >> 9) & 15;
      const int l2 = (idx >> 3) & 63;
      const int c2 = l2 & 15, q2 = l2 >> 4;
      const int j = idx & 7;
      wvfrag[idx] = f2bf(wv[(q2 * 8 + j) * CC + t * 16 + c2]);
    }
  }
  const int t0 = blockIdx.x * 64 + wave * 16;
  short8 af[8];
  const float* xr = x + (long)(t0 + col) * CC + q * 8;
#pragma unroll
  for (int kc = 0; kc < 8; ++kc) {
    float tmp[8];
    *(float4*)(tmp) = *(const float4*)(xr + kc * 32);
    *(float4*)(tmp + 4) = *(const float4*)(xr + kc * 32 + 4);
    short8 o;
#pragma unroll
    for (int j = 0; j < 8; ++j) o[j] = (short)f2bf(tmp[j]);
    af[kc] = o;
  }
  __syncthreads();
  const floatx4 zero = {0.f, 0.f, 0.f, 0.f};
  floatx4 acc[3][2];
#pragma unroll
  for (int m = 0; m < 3; ++m) { acc[m][0] = zero; acc[m][1] = zero; }
#pragma unroll
  for (int kc = 0; kc < 8; ++kc) {
#pragma unroll
    for (int mat = 0; mat < 3; ++mat) {
#pragma unroll
      for (int nt = 0; nt < 2; ++nt) {
        const short8 bf = *(const short8*)(wflds + (mat * 16 + kc * 2 + nt) * 512 + lane * 8);
        acc[mat][nt] = MFMA16(af[kc], bf, acc[mat][nt], 0, 0, 0);
      }
    }
  }
  const int b = t0 >> 12;
#pragma unroll
  for (int nt = 0; nt < 2; ++nt) {
#pragma unroll
    for (int r = 0; r < 4; ++r) {
      const int tok = t0 + q * 4 + r;
      const int n = nt * 16 + col;
      f16[(long)tok * RR + n] = f2bf(acc[0][nt][r] * LOG2E);
      g16[(long)tok * RR + n] = f2bf(acc[1][nt][r]);
      // hT stored interleaved within each 32-m chunk: logical m = hi*16+qq*4+j
      // lands at s = qq*8 + hi*4 + j (so pvout's short8 @ m0+q*8 yields both
      // K=16 B-frags). Here qq=q, j=r, hi=(tok>>4)&1.
      const int tl = tok & (NN - 1);
      const int sp = (tl & ~31) | (q << 3) | ((tl & 16) >> 2) | r;
      hT16[((long)b * RR + n) * NN + sp] = f2bf(acc[2][nt][r]);
    }
  }
}

// --------------------- k_colsum: psum[seg][b][m] = sum_{n in seg} exp2(s'[n,m])
// 2048 blocks (8/CU, 8 waves/SIMD): block = (seg, b, 32-m); 4 waves split the
// seg's n-range (16 iters/wave); LDS cross-wave reduce; raw partials (no log).
__global__ __launch_bounds__(256) void k_colsum(
    const unsigned short* __restrict__ f16, const unsigned short* __restrict__ g16,
    float* __restrict__ psum) {
  __shared__ float red[4][32];
  const int tid = threadIdx.x, lane = tid & 63, wave = tid >> 6;
  const int col = lane & 15, q = lane >> 4;
  const int mblk = blockIdx.x & 127;
  const int b = (blockIdx.x >> 7) & 3;
  const int seg = blockIdx.x >> 9;
  const int m0 = mblk * 32;
  const short8 bg1 = *(const short8*)(g16 + ((long)(b * NN + m0 + col)) * RR + q * 8);
  const short8 bg2 = *(const short8*)(g16 + ((long)(b * NN + m0 + 16 + col)) * RR + q * 8);
  const floatx4 zero = {0.f, 0.f, 0.f, 0.f};
  float s1 = 0.f, s2 = 0.f;
  const unsigned short* fb =
      f16 + ((long)b * NN + seg * (NN / CSEG) + wave * (NN / CSEG / 4)) * RR;
#pragma unroll 4
  for (int n = 0; n < NN / CSEG / 4; n += 16) {
    const short8 af = *(const short8*)(fb + (long)(n + col) * RR + q * 8);
    const floatx4 d1 = MFMA16(af, bg1, zero, 0, 0, 0);
    const floatx4 d2 = MFMA16(af, bg2, zero, 0, 0, 0);
    s1 += __builtin_amdgcn_exp2f(d1[0]) + __builtin_amdgcn_exp2f(d1[1]) +
          __builtin_amdgcn_exp2f(d1[2]) + __builtin_amdgcn_exp2f(d1[3]);
    s2 += __builtin_amdgcn_exp2f(d2[0]) + __builtin_amdgcn_exp2f(d2[1]) +
          __builtin_amdgcn_exp2f(d2[2]) + __builtin_amdgcn_exp2f(d2[3]);
  }
  s1 += __shfl_xor(s1, 16); s1 += __shfl_xor(s1, 32);
  s2 += __shfl_xor(s2, 16); s2 += __shfl_xor(s2, 32);
  if (lane < 16) {
    red[wave][lane] = s1;
    red[wave][lane + 16] = s2;
  }
  __syncthreads();
  if (tid < 32) {
    psum[(long)seg * (BB * NN) + b * NN + m0 + tid] =
        red[0][tid] + red[1][tid] + red[2][tid] + red[3][tid];
  }
}

// --------- k_pvout: 512-thread block = 32 tokens; 8 waves = m-eighths.
// Prologue: bias[m] = -log2(sum_seg psum[seg][b][m]) into 16 KB LDS (once).
// S^T MFMA with C = bias[m] -> exp2(d) = P in (0,1] already normalized;
// S^T C/D layout IS the 16x16x16 A-frag layout, so PV runs in-register.
__global__ __launch_bounds__(512, 4) void k_pvout(
    const unsigned short* __restrict__ f16, const unsigned short* __restrict__ g16,
    const unsigned short* __restrict__ hT16, const float* __restrict__ psum,
    const unsigned short* __restrict__ wvfrag, const float* __restrict__ x,
    const float* __restrict__ gamma, float* __restrict__ out) {
  __shared__ float ylds[8][32 * 36];    // 36 KB: per-wave y partials
  __shared__ float sc_all[8][16 * 36];  // 18 KB: epilogue store-swizzle scratch
  __shared__ float bias[NN];            // 16 KB: -log2(colsum) per m
  const int tid = threadIdx.x, lane = tid & 63, wave = tid >> 6;  // 0..7
  const int col = lane & 15, q = lane >> 4;
  const int b = blockIdx.x >> 7;
  const int t0 = (blockIdx.x & 127) * 32;  // token base (in-batch), 32 tokens
  const floatx4 zero = {0.f, 0.f, 0.f, 0.f};
  {  // bias prologue: thread t -> m = t*8..t*8+7 (coalesced float4 loads)
    float cs[8] = {0.f, 0.f, 0.f, 0.f, 0.f, 0.f, 0.f, 0.f};
#pragma unroll
    for (int sg = 0; sg < CSEG; ++sg) {
      const float* p = psum + (long)sg * (BB * NN) + b * NN + tid * 8;
      const float4 a = *(const float4*)p;
      const float4 c = *(const float4*)(p + 4);
      cs[0] += a.x; cs[1] += a.y; cs[2] += a.z; cs[3] += a.w;
      cs[4] += c.x; cs[5] += c.y; cs[6] += c.z; cs[7] += c.w;
    }
#pragma unroll
    for (int j = 0; j < 8; ++j) bias[tid * 8 + j] = -__builtin_amdgcn_logf(cs[j]);
  }
  // B-frags of S^T: f rows for the block's 32 tokens (loop-invariant)
  const short8 af1 = *(const short8*)(f16 + ((long)(b * NN + t0 + col)) * RR + q * 8);
  const short8 af2 = *(const short8*)(f16 + ((long)(b * NN + t0 + 16 + col)) * RR + q * 8);
  floatx4 a11 = zero, a12 = zero, a21 = zero, a22 = zero;
  const unsigned short* gb = g16 + (long)b * NN * RR;
  const unsigned short* hb = hT16 + (long)b * RR * NN;
  const int mq = wave * 512;  // this wave's m-eighth
  __syncthreads();            // bias table ready
#pragma unroll 2
  for (int mi = 0; mi < 512; mi += 32) {
    const int m0 = mq + mi;
    const short8 bg1 = *(const short8*)(gb + (long)(m0 + col) * RR + q * 8);
    const short8 bg2 = *(const short8*)(gb + (long)(m0 + 16 + col) * RR + q * 8);
    // interleaved hT: elements 0..3 = h[m0+q*4+j][r], 4..7 = h[m0+16+q*4+j][r]
    const short8 hv1 = *(const short8*)(hb + (long)col * NN + m0 + q * 8);
    const short8 hv2 = *(const short8*)(hb + (long)(col + 16) * NN + m0 + q * 8);
    // softmax bias as MFMA C-operand from LDS: lane reg r <-> m = m0 + q*4 + r
    const floatx4 cm0 = *(const floatx4*)(bias + m0 + q * 4);
    const floatx4 cm1 = *(const floatx4*)(bias + m0 + 16 + q * 4);
    // S^T + bias: A=g(m rows), B=f(n cols) -> lane: s'[n=col][m=m0+q*4+r]-lg2cs
    const floatx4 d00 = MFMA16(bg1, af1, cm0, 0, 0, 0);  // n-blk 0,  m-blk 0
    const floatx4 d01 = MFMA16(bg2, af1, cm1, 0, 0, 0);  // n-blk 0,  m-blk 16
    const floatx4 d10 = MFMA16(bg1, af2, cm0, 0, 0, 0);  // n-blk 16, m-blk 0
    const floatx4 d11 = MFMA16(bg2, af2, cm1, 0, 0, 0);  // n-blk 16, m-blk 16
    // P = exp2(d) in (0,1], packed in-register as 16x16x16 A-frags (k=q*4+j)
    union PU { unsigned u[2]; short4v s; } p00, p01, p10, p11;
    p00.u[0] = bfpack(__builtin_amdgcn_exp2f(d00[0]), __builtin_amdgcn_exp2f(d00[1]));
    p00.u[1] = bfpack(__builtin_amdgcn_exp2f(d00[2]), __builtin_amdgcn_exp2f(d00[3]));
    p01.u[0] = bfpack(__builtin_amdgcn_exp2f(d01[0]), __builtin_amdgcn_exp2f(d01[1]));
    p01.u[1] = bfpack(__builtin_amdgcn_exp2f(d01[2]), __builtin_amdgcn_exp2f(d01[3]));
    p10.u[0] = bfpack(__builtin_amdgcn_exp2f(d10[0]), __builtin_amdgcn_exp2f(d10[1]));
    p10.u[1] = bfpack(__builtin_amdgcn_exp2f(d10[2]), __builtin_amdgcn_exp2f(d10[3]));
    p11.u[0] = bfpack(__builtin_amdgcn_exp2f(d11[0]), __builtin_amdgcn_exp2f(d11[1]));
    p11.u[1] = bfpack(__builtin_amdgcn_exp2f(d11[2]), __builtin_amdgcn_exp2f(d11[3]));
    const short4v bh1lo = __builtin_shufflevector(hv1, hv1, 0, 1, 2, 3);
    const short4v bh1hi = __builtin_shufflevector(hv1, hv1, 4, 5, 6, 7);
    const short4v bh2lo = __builtin_shufflevector(hv2, hv2, 0, 1, 2, 3);
    const short4v bh2hi = __builtin_shufflevector(hv2, hv2, 4, 5, 6, 7);
    // PV: y[n][r] += P[n][m] h[m][r], two K=16 chunks per 32-m iteration
    a11 = MFMA16K(p00.s, bh1lo, a11, 0, 0, 0);
    a11 = MFMA16K(p01.s, bh1hi, a11, 0, 0, 0);
    a12 = MFMA16K(p00.s, bh2lo, a12, 0, 0, 0);
    a12 = MFMA16K(p01.s, bh2hi, a12, 0, 0, 0);
    a21 = MFMA16K(p10.s, bh1lo, a21, 0, 0, 0);
    a21 = MFMA16K(p11.s, bh1hi, a21, 0, 0, 0);
    a22 = MFMA16K(p10.s, bh2lo, a22, 0, 0, 0);
    a22 = MFMA16K(p11.s, bh2hi, a22, 0, 0, 0);
  }
  // stash y partial for this m-eighth: [wave][token 0..31][r 0..31]
  {
    float* yp = &ylds[wave][0];
#pragma unroll
    for (int r = 0; r < 4; ++r) {
      yp[(q * 4 + r) * 36 + col] = a11[r];
      yp[(q * 4 + r) * 36 + col + 16] = a12[r];
      yp[(16 + q * 4 + r) * 36 + col] = a21[r];
      yp[(16 + q * 4 + r) * 36 + col + 16] = a22[r];
    }
  }
  __syncthreads();
  // epilogue: wave -> (tile = w&1: 16 tokens, hh = w>>1: 64-channel quarter)
  {
    const int tile = wave & 1, hh = wave >> 1;  // hh in 0..3
    float s[8] = {0.f, 0.f, 0.f, 0.f, 0.f, 0.f, 0.f, 0.f};
#pragma unroll
    for (int w2 = 0; w2 < 8; ++w2) {
      const float* yp = &ylds[w2][(tile * 16 + col) * 36 + q * 8];
      const float4 u0 = *(const float4*)yp;
      const float4 u1 = *(const float4*)(yp + 4);
      s[0] += u0.x; s[1] += u0.y; s[2] += u0.z; s[3] += u0.w;
      s[4] += u1.x; s[5] += u1.y; s[6] += u1.z; s[7] += u1.w;
    }
    short8 ay;
#pragma unroll
    for (int j = 0; j < 8; ++j) ay[j] = (short)f2bf(s[j]);
    const float gm = gamma[0];
    float* sc = &sc_all[wave][0];  // per-wave scratch, 16 x 36 floats
    const int row = lane >> 2, c4 = (lane & 3) * 4;
#pragma unroll
    for (int tp = 0; tp < 4; tp += 2) {
      const short8 bw0 = *(const short8*)(wvfrag + (hh * 4 + tp) * 512 + lane * 8);
      const short8 bw1 = *(const short8*)(wvfrag + (hh * 4 + tp + 1) * 512 + lane * 8);
      const floatx4 d0 = MFMA16(ay, bw0, zero, 0, 0, 0);
      const floatx4 d1 = MFMA16(ay, bw1, zero, 0, 0, 0);
#pragma unroll
      for (int r = 0; r < 4; ++r) {
        sc[(q * 4 + r) * 36 + col] = d0[r];
        sc[(q * 4 + r) * 36 + col + 16] = d1[r];
      }
      // same-wave readback, row-major -> coalesced float4 global I/O
#pragma unroll
      for (int j = 0; j < 2; ++j) {
        const float4 v = *(const float4*)(sc + row * 36 + c4 + j * 16);
        const long gidx = (long)(b * NN + t0 + tile * 16 + row) * CC +
                          hh * 64 + tp * 16 + j * 16 + c4;
        const float4 xv = *(const float4*)(x + gidx);
        float4 o;
        o.x = gm * v.x + xv.x; o.y = gm * v.y + xv.y;
        o.z = gm * v.z + xv.z; o.w = gm * v.w + xv.w;
        *(float4*)(out + gidx) = o;
      }
    }
  }
}

extern "C" void kernel_launch(void* const* d_in, const int* in_sizes, int n_in,
                              void* d_out, int out_size, void* d_ws, size_t ws_size,
                              hipStream_t stream) {
  const float* x = (const float*)d_in[0];
  const float* wf = (const float*)d_in[1];
  const float* wg = (const float*)d_in[2];
  const float* wh = (const float*)d_in[3];
  const float* wv = (const float*)d_in[4];
  const float* gamma = (const float*)d_in[5];
  float* out = (float*)d_out;

  unsigned short* f16 = (unsigned short*)d_ws;           // B*N*R (x LOG2E)
  unsigned short* g16 = f16 + (long)BB * NN * RR;        // B*N*R
  unsigned short* hT16 = g16 + (long)BB * NN * RR;       // B*R*N (m-interleaved)
  unsigned short* wvfrag = hT16 + (long)BB * NN * RR;    // 8192
  float* psum = (float*)(wvfrag + 8192);                 // CSEG*B*N partials

  k_fgh<<<BB * NN / 64, 256, 0, stream>>>(x, wf, wg, wh, wv, f16, g16, hT16, wvfrag);
  k_colsum<<<CSEG * BB * 128, 256, 0, stream>>>(f16, g16, psum);
  k_pvout<<<BB * 128, 512, 0, stream>>>(f16, g16, hT16, psum, wvfrag, x, gamma, out);
}